// Round 8
// baseline (115.338 us; speedup 1.0000x reference)
//
#include <hip/hip_runtime.h>

#define NREL 32

typedef short short8 __attribute__((ext_vector_type(8)));
typedef float f32x4 __attribute__((ext_vector_type(4)));

__device__ inline unsigned short f2bf(float f) {
    union { float f; unsigned u; } u; u.f = f;
    unsigned r = u.u + 0x7FFF + ((u.u >> 16) & 1);   // RNE
    return (unsigned short)(r >> 16);
}

// ---------------------------------------------------------------------------
// ws layout:
//   wtb  [2*32*4096] ushort  bf16 normalized tables, TRANSPOSED:
//                            wtb[(dir*32+r)*4096 + o*64 + i]
//   xbf  [N*64] ushort       bf16(x)
//   cntf [N] f32             # edges with src==n      (zeroed by memset)
//   cntb [N] f32             # edges with dst==n      (zeroed by memset)
//   fill [32] int            per-rel edge count / cursors (zeroed by memset)
//   einfo[32*CAP] int2       {src, dst} per edge, fixed-capacity rel buckets
// ---------------------------------------------------------------------------

// Fused independent setup: blocks [0,nCountB) count degrees + scatter into
// fixed-capacity rel buckets; [nCountB,nCountB+64) normalize+transpose
// weights; the rest do out = x@lin_w^T + b and write xbf = bf16(x).
__global__ __launch_bounds__(256) void setup_kernel(
        const float* __restrict__ x,
        const int* __restrict__ src, const int* __restrict__ dst,
        const int* __restrict__ et,
        const float* __restrict__ wf, const float* __restrict__ wb,
        const float* __restrict__ lw, const float* __restrict__ lb,
        float* __restrict__ cntf, float* __restrict__ cntb,
        int* __restrict__ fill, unsigned short* __restrict__ wtb,
        unsigned short* __restrict__ xbf, int2* __restrict__ einfo,
        float* __restrict__ out, int E, int N, int nCountB, int CAP) {
    __shared__ float smem[4 * 16 * 64 + 8];
    int tid = threadIdx.x;
    int b = blockIdx.x;

    if (b < nCountB) {
        // ---- count + scatter role (block-aggregated cursors) ----
        int* lh = (int*)smem;          // [0..31] per-rel block count
        int* lbase = lh + NREL;        // [32..63] reserved global base
        if (tid < 2 * NREL) lh[tid] = 0;
        __syncthreads();
        int e = b * 256 + tid;
        int s = 0, d = 0, r = 0, my = 0;
        bool valid = (e < E);
        if (valid) {
            s = src[e]; d = dst[e]; r = et[e];
            atomicAdd(&cntf[s], 1.0f);
            atomicAdd(&cntb[d], 1.0f);
            my = atomicAdd(&lh[r], 1);
        }
        __syncthreads();
        if (tid < NREL && lh[tid]) lbase[tid] = atomicAdd(&fill[tid], lh[tid]);
        __syncthreads();
        if (valid) einfo[r * CAP + lbase[r] + my] = make_int2(s, d);
        return;
    }
    b -= nCountB;
    if (b < 64) {
        // ---- norm role: normalize fp32 table row, write bf16 transposed ----
        int rel = b & 31, tab = b >> 5;
        const float* s_ = (tab ? wb : wf) + rel * 4096;
        unsigned short* d_ = wtb + (size_t)b * 4096;
        float* part = smem;
        float ssum = 0.f;
        #pragma unroll
        for (int k = 0; k < 16; k += 4) {
            float4 v = *(const float4*)(s_ + tid * 16 + k);
            ssum += v.x * v.x + v.y * v.y + v.z * v.z + v.w * v.w;
        }
        #pragma unroll
        for (int off = 32; off >= 1; off >>= 1) ssum += __shfl_down(ssum, off, 64);
        if ((tid & 63) == 0) part[tid >> 6] = ssum;
        __syncthreads();
        if (tid == 0) part[4] = 1.0f / (sqrtf(part[0] + part[1] + part[2] + part[3]) + 0.01f);
        __syncthreads();
        float sc = part[4];
        int i = tid >> 2, o0 = (tid & 3) * 16;
        #pragma unroll
        for (int q = 0; q < 4; ++q) {
            float4 v = *(const float4*)(s_ + i * 64 + o0 + q * 4);
            d_[(o0 + q * 4 + 0) * 64 + i] = f2bf(v.x * sc);
            d_[(o0 + q * 4 + 1) * 64 + i] = f2bf(v.y * sc);
            d_[(o0 + q * 4 + 2) * 64 + i] = f2bf(v.z * sc);
            d_[(o0 + q * 4 + 3) * 64 + i] = f2bf(v.w * sc);
        }
        return;
    }
    b -= 64;
    // ---- linear + xbf role: 64 nodes/block (halves lin_w reload traffic) --
    {
        int lane = tid & 63, w = tid >> 6;
        int nodeBase = b * 64 + w * 16;
        float4 wrow[16];
        const float4* lwrow = (const float4*)(lw + lane * 64);
        #pragma unroll
        for (int g = 0; g < 16; ++g) wrow[g] = lwrow[g];
        float bias = lb[lane];
        float* xs = smem + w * 16 * 64;
        #pragma unroll
        for (int t = 0; t < 16; ++t) {
            int n = nodeBase + t;
            if (n < N) {
                float v = x[(size_t)n * 64 + lane];
                xs[t * 64 + lane] = v;
                xbf[(size_t)n * 64 + lane] = f2bf(v);
            }
        }
        __syncthreads();
        for (int t = 0; t < 16; ++t) {
            int n = nodeBase + t;
            if (n >= N) break;
            float acc = bias;
            const float4* xr = (const float4*)(xs + t * 64);
            #pragma unroll
            for (int g = 0; g < 16; ++g) {
                float4 xv = xr[g];
                acc = fmaf(xv.x, wrow[g].x, acc);
                acc = fmaf(xv.y, wrow[g].y, acc);
                acc = fmaf(xv.z, wrow[g].z, acc);
                acc = fmaf(xv.w, wrow[g].w, acc);
            }
            out[(size_t)n * 64 + lane] = acc;
        }
    }
}

// One block per (128-edge chunk) x (direction = blockIdx.y). Each wave owns
// two 16-row M-tiles (rows w*16+. and 64+w*16+.) sharing every Bs LDS read.
#define APITCH 72  // 64 + 8 shorts pad
__global__ __launch_bounds__(256) void conv_mfma(
        const unsigned short* __restrict__ xbf,
        const float* __restrict__ cntf, const float* __restrict__ cntb,
        const int* __restrict__ fill,
        const unsigned short* __restrict__ wtb,
        const int2* __restrict__ einfo,
        float* __restrict__ out, int CAP) {
    int tid = threadIdx.x;
    int lane = tid & 63;

    // 128-edge chunk-count scan over fill[32]
    int fr = (lane < NREL) ? fill[lane] : 0;
    int ch = (fr + 127) >> 7;
    int s_scan = ch;
    #pragma unroll
    for (int off = 1; off < 32; off <<= 1) {
        int t = __shfl_up(s_scan, off, 64);
        if ((lane & 31) >= off) s_scan += t;
    }
    int chExcl = s_scan - ch;

    int c = blockIdx.x;
    unsigned long long mm = __ballot(lane < NREL && c >= chExcl && c < chExcl + ch);
    if (mm == 0) return;                    // past last chunk (uniform)
    int rel = __ffsll(mm) - 1;
    int lc = c - __shfl(chExcl, rel, 64);
    int frr = __shfl(fr, rel, 64);
    int pos = rel * CAP + lc * 128;
    int valid = frr - lc * 128;
    if (valid > 128) valid = 128;
    int dir = blockIdx.y;

    __shared__ unsigned short As[128 * APITCH];  // As[j][i] = bf16(x[s_j][i])
    __shared__ unsigned short Bs[64 * APITCH];   // Bs[o][i] = Wn[i][o]
    __shared__ int dstS[128];
    __shared__ float invS[128];

    int j0 = tid >> 2, part = tid & 3;

    // stage B (transposed table is a straight copy)
    {
        const uint4* s4 = (const uint4*)(wtb + (size_t)((dir << 5) + rel) * 4096 + j0 * 64 + part * 16);
        uint4 v0 = s4[0], v1 = s4[1];
        *(uint4*)(&Bs[j0 * APITCH + part * 16]) = v0;
        *(uint4*)(&Bs[j0 * APITCH + part * 16 + 8]) = v1;
    }

    // stage A: two row-sets of 64; 1/deg computed here (counts final)
    #pragma unroll
    for (int rs = 0; rs < 2; ++rs) {
        int j = j0 + (rs << 6);
        unsigned short* arow = &As[j * APITCH + part * 16];
        if (j >= valid) {
            uint4 z = {0, 0, 0, 0};
            *(uint4*)(arow) = z;
            *(uint4*)(arow + 8) = z;
            if (part == 0) { dstS[j] = -1; invS[j] = 0.f; }
        } else {
            int2 v = einfo[pos + j];
            int s_ = dir ? v.y : v.x;
            int d_ = dir ? v.x : v.y;
            const uint4* xr = (const uint4*)(xbf + (size_t)s_ * 64);
            uint4 a0 = xr[part * 2], a1 = xr[part * 2 + 1];
            *(uint4*)(arow) = a0;
            *(uint4*)(arow + 8) = a1;
            if (part == 0) {
                float cv = dir ? cntb[s_] : cntf[s_];
                dstS[j] = d_;
                invS[j] = 1.0f / (cv + 1.0f);
            }
        }
    }
    __syncthreads();

    // MFMA: wave w computes rows {w*16..+15} and {64+w*16..+15} x 64 channels
    int w = tid >> 6;
    int m = lane & 15, quad = lane >> 4;
    f32x4 zero4 = {0.f, 0.f, 0.f, 0.f};
    f32x4 acc[2][4] = {{zero4, zero4, zero4, zero4}, {zero4, zero4, zero4, zero4}};
    #pragma unroll
    for (int k0 = 0; k0 < 64; k0 += 32) {
        short8 aLo = *(const short8*)(&As[(w * 16 + m) * APITCH + k0 + quad * 8]);
        short8 aHi = *(const short8*)(&As[(64 + w * 16 + m) * APITCH + k0 + quad * 8]);
        #pragma unroll
        for (int n = 0; n < 4; ++n) {
            short8 bn = *(const short8*)(&Bs[(n * 16 + m) * APITCH + k0 + quad * 8]);
            acc[0][n] = __builtin_amdgcn_mfma_f32_16x16x32_bf16(aLo, bn, acc[0][n], 0, 0, 0);
            acc[1][n] = __builtin_amdgcn_mfma_f32_16x16x32_bf16(aHi, bn, acc[1][n], 0, 0, 0);
        }
    }

    // epilogue: C/D layout col=lane&15, row=quad*4+reg; scale by 1/deg in fp32
    #pragma unroll
    for (int half = 0; half < 2; ++half) {
        int row_base = half * 64 + w * 16 + quad * 4;
        #pragma unroll
        for (int r = 0; r < 4; ++r) {
            int row = row_base + r;
            int d_ = dstS[row];
            if (d_ >= 0) {
                float inv = invS[row];
                float* op = out + (size_t)d_ * 64 + m;
                atomicAdd(op +  0, acc[half][0][r] * inv);
                atomicAdd(op + 16, acc[half][1][r] * inv);
                atomicAdd(op + 32, acc[half][2][r] * inv);
                atomicAdd(op + 48, acc[half][3][r] * inv);
            }
        }
    }
}

extern "C" void kernel_launch(void* const* d_in, const int* in_sizes, int n_in,
                              void* d_out, int out_size, void* d_ws, size_t ws_size,
                              hipStream_t stream) {
    const float* x  = (const float*)d_in[0];
    const int*   ei = (const int*)  d_in[1];
    const int*   et = (const int*)  d_in[2];
    const float* wf = (const float*)d_in[3];
    const float* wb = (const float*)d_in[4];
    const float* lw = (const float*)d_in[5];
    const float* lb = (const float*)d_in[6];
    float* out = (float*)d_out;

    const int E = in_sizes[2];
    const int N = in_sizes[0] / 64;
    const int CAP = ((E + 63) >> 6) << 6;            // per-rel bucket capacity
    const int maxC = ((E + 127) >> 7) + NREL;        // 128-edge chunks upper bound

    char* p = (char*)d_ws;
    unsigned short* wtb = (unsigned short*)p;  p += (size_t)2 * NREL * 4096 * sizeof(unsigned short);
    unsigned short* xbf = (unsigned short*)p;  p += (size_t)N * 64 * sizeof(unsigned short);
    float* cntf = (float*)p;                   p += (size_t)N * sizeof(float);
    float* cntb = (float*)p;                   p += (size_t)N * sizeof(float);
    int*   fill = (int*)p;                     p += NREL * sizeof(int);
    int2*  einfo = (int2*)p;                   p += (size_t)NREL * CAP * sizeof(int2);

    const int* srcp = ei;
    const int* dstp = ei + E;

    // zero cntf, cntb, fill (contiguous)
    hipMemsetAsync(cntf, 0, ((size_t)2 * N + NREL) * sizeof(float), stream);

    const int nCountB = (E + 255) / 256;
    const int nLinB   = (N + 63) / 64;
    setup_kernel<<<nCountB + 64 + nLinB, 256, 0, stream>>>(
        x, srcp, dstp, et, wf, wb, lw, lb, cntf, cntb, fill, wtb, xbf, einfo,
        out, E, N, nCountB, CAP);
    dim3 cgrid(maxC, 2);
    conv_mfma<<<cgrid, 256, 0, stream>>>(xbf, cntf, cntb, fill, wtb, einfo, out, CAP);
}

// Round 9
// 113.167 us; speedup vs baseline: 1.0192x; 1.0192x over previous
//
#include <hip/hip_runtime.h>

#define NREL 32

typedef short short8 __attribute__((ext_vector_type(8)));
typedef float f32x4 __attribute__((ext_vector_type(4)));

__device__ inline unsigned short f2bf(float f) {
    union { float f; unsigned u; } u; u.f = f;
    unsigned r = u.u + 0x7FFF + ((u.u >> 16) & 1);   // RNE
    return (unsigned short)(r >> 16);
}

// ---------------------------------------------------------------------------
// ws layout:
//   wtb  [2*32*4096] ushort  bf16 normalized tables, TRANSPOSED:
//                            wtb[(dir*32+r)*4096 + o*64 + i]
//   xbf  [N*64] ushort       bf16(x)
//   cntf [N] f32             # edges with src==n      (zeroed by memset)
//   cntb [N] f32             # edges with dst==n      (zeroed by memset)
//   fill [32] int            per-rel edge count / cursors (zeroed by memset)
//   einfo[32*CAP] int2       {src, dst} per edge, fixed-capacity rel buckets
// ---------------------------------------------------------------------------

// Fused independent setup: blocks [0,nCountB) count degrees + scatter into
// fixed-capacity rel buckets; [nCountB,nCountB+64) normalize+transpose
// weights; the rest do out = x@lin_w^T + b and write xbf = bf16(x).
__global__ __launch_bounds__(256) void setup_kernel(
        const float* __restrict__ x,
        const int* __restrict__ src, const int* __restrict__ dst,
        const int* __restrict__ et,
        const float* __restrict__ wf, const float* __restrict__ wb,
        const float* __restrict__ lw, const float* __restrict__ lb,
        float* __restrict__ cntf, float* __restrict__ cntb,
        int* __restrict__ fill, unsigned short* __restrict__ wtb,
        unsigned short* __restrict__ xbf, int2* __restrict__ einfo,
        float* __restrict__ out, int E, int N, int nCountB, int CAP) {
    __shared__ float smem[4 * 8 * 64 + 8];
    int tid = threadIdx.x;
    int b = blockIdx.x;

    if (b < nCountB) {
        // ---- count + scatter role (block-aggregated cursors) ----
        int* lh = (int*)smem;          // [0..31] per-rel block count
        int* lbase = lh + NREL;        // [32..63] reserved global base
        if (tid < 2 * NREL) lh[tid] = 0;
        __syncthreads();
        int e = b * 256 + tid;
        int s = 0, d = 0, r = 0, my = 0;
        bool valid = (e < E);
        if (valid) {
            s = src[e]; d = dst[e]; r = et[e];
            atomicAdd(&cntf[s], 1.0f);
            atomicAdd(&cntb[d], 1.0f);
            my = atomicAdd(&lh[r], 1);
        }
        __syncthreads();
        if (tid < NREL && lh[tid]) lbase[tid] = atomicAdd(&fill[tid], lh[tid]);
        __syncthreads();
        if (valid) einfo[r * CAP + lbase[r] + my] = make_int2(s, d);
        return;
    }
    b -= nCountB;
    if (b < 64) {
        // ---- norm role: normalize fp32 table row, write bf16 transposed ----
        int rel = b & 31, tab = b >> 5;
        const float* s_ = (tab ? wb : wf) + rel * 4096;
        unsigned short* d_ = wtb + (size_t)b * 4096;
        float* part = smem;
        float ssum = 0.f;
        #pragma unroll
        for (int k = 0; k < 16; k += 4) {
            float4 v = *(const float4*)(s_ + tid * 16 + k);
            ssum += v.x * v.x + v.y * v.y + v.z * v.z + v.w * v.w;
        }
        #pragma unroll
        for (int off = 32; off >= 1; off >>= 1) ssum += __shfl_down(ssum, off, 64);
        if ((tid & 63) == 0) part[tid >> 6] = ssum;
        __syncthreads();
        if (tid == 0) part[4] = 1.0f / (sqrtf(part[0] + part[1] + part[2] + part[3]) + 0.01f);
        __syncthreads();
        float sc = part[4];
        int i = tid >> 2, o0 = (tid & 3) * 16;
        #pragma unroll
        for (int q = 0; q < 4; ++q) {
            float4 v = *(const float4*)(s_ + i * 64 + o0 + q * 4);
            d_[(o0 + q * 4 + 0) * 64 + i] = f2bf(v.x * sc);
            d_[(o0 + q * 4 + 1) * 64 + i] = f2bf(v.y * sc);
            d_[(o0 + q * 4 + 2) * 64 + i] = f2bf(v.z * sc);
            d_[(o0 + q * 4 + 3) * 64 + i] = f2bf(v.w * sc);
        }
        return;
    }
    b -= 64;
    // ---- linear + xbf role: 32 nodes/block (round-7 proven config) ----
    {
        int lane = tid & 63, w = tid >> 6;
        int nodeBase = b * 32 + w * 8;
        float4 wrow[16];
        const float4* lwrow = (const float4*)(lw + lane * 64);
        #pragma unroll
        for (int g = 0; g < 16; ++g) wrow[g] = lwrow[g];
        float bias = lb[lane];
        float* xs = smem + w * 8 * 64;
        #pragma unroll
        for (int t = 0; t < 8; ++t) {
            int n = nodeBase + t;
            if (n < N) {
                float v = x[(size_t)n * 64 + lane];
                xs[t * 64 + lane] = v;
                xbf[(size_t)n * 64 + lane] = f2bf(v);
            }
        }
        __syncthreads();
        for (int t = 0; t < 8; ++t) {
            int n = nodeBase + t;
            if (n >= N) break;
            float acc = bias;
            const float4* xr = (const float4*)(xs + t * 64);
            #pragma unroll
            for (int g = 0; g < 16; ++g) {
                float4 xv = xr[g];
                acc = fmaf(xv.x, wrow[g].x, acc);
                acc = fmaf(xv.y, wrow[g].y, acc);
                acc = fmaf(xv.z, wrow[g].z, acc);
                acc = fmaf(xv.w, wrow[g].w, acc);
            }
            out[(size_t)n * 64 + lane] = acc;
        }
    }
}

// One block per 64-edge chunk, BOTH directions: shared einfo read, shared
// chunk scan, shared prologue; fwd/bwd differ only in B table, gathered A
// rows, and scatter target. Halves block count & einfo traffic vs grid.y=2.
#define APITCH 72  // 64 + 8 shorts pad
__global__ __launch_bounds__(256) void conv_mfma(
        const unsigned short* __restrict__ xbf,
        const float* __restrict__ cntf, const float* __restrict__ cntb,
        const int* __restrict__ fill,
        const unsigned short* __restrict__ wtb,
        const int2* __restrict__ einfo,
        float* __restrict__ out, int CAP) {
    int tid = threadIdx.x;
    int lane = tid & 63;

    // 64-edge chunk-count scan over fill[32]
    int fr = (lane < NREL) ? fill[lane] : 0;
    int ch = (fr + 63) >> 6;
    int s_scan = ch;
    #pragma unroll
    for (int off = 1; off < 32; off <<= 1) {
        int t = __shfl_up(s_scan, off, 64);
        if ((lane & 31) >= off) s_scan += t;
    }
    int chExcl = s_scan - ch;

    int c = blockIdx.x;
    unsigned long long mm = __ballot(lane < NREL && c >= chExcl && c < chExcl + ch);
    if (mm == 0) return;                    // past last chunk (uniform)
    int rel = __ffsll(mm) - 1;
    int lc = c - __shfl(chExcl, rel, 64);
    int frr = __shfl(fr, rel, 64);
    int pos = rel * CAP + lc * 64;
    int valid = frr - lc * 64;
    if (valid > 64) valid = 64;

    __shared__ unsigned short Af[64 * APITCH];  // bf16(x[src_j])
    __shared__ unsigned short Ab[64 * APITCH];  // bf16(x[dst_j])
    __shared__ unsigned short Bf[64 * APITCH];  // Wnf[i][o] (o-major)
    __shared__ unsigned short Bb[64 * APITCH];  // Wnb[i][o]
    __shared__ int dstF[64], dstB[64];
    __shared__ float invF[64], invB[64];

    int j = tid >> 2, part = tid & 3;

    // stage B: both tables (straight copies of transposed tables)
    {
        size_t off = (size_t)rel * 4096 + j * 64 + part * 16;
        const uint4* sf = (const uint4*)(wtb + off);
        const uint4* sb = (const uint4*)(wtb + (size_t)NREL * 4096 + off);
        uint4 f0 = sf[0], f1 = sf[1], b0 = sb[0], b1 = sb[1];
        *(uint4*)(&Bf[j * APITCH + part * 16]) = f0;
        *(uint4*)(&Bf[j * APITCH + part * 16 + 8]) = f1;
        *(uint4*)(&Bb[j * APITCH + part * 16]) = b0;
        *(uint4*)(&Bb[j * APITCH + part * 16 + 8]) = b1;
    }

    // stage A: gather both endpoints' rows; 1/deg here (counts final)
    if (j >= valid) {
        uint4 z = {0, 0, 0, 0};
        *(uint4*)(&Af[j * APITCH + part * 16]) = z;
        *(uint4*)(&Af[j * APITCH + part * 16 + 8]) = z;
        *(uint4*)(&Ab[j * APITCH + part * 16]) = z;
        *(uint4*)(&Ab[j * APITCH + part * 16 + 8]) = z;
        if (part == 0) { dstF[j] = -1; dstB[j] = -1; invF[j] = 0.f; invB[j] = 0.f; }
    } else {
        int2 v = einfo[pos + j];                 // {src, dst}
        const uint4* xs = (const uint4*)(xbf + (size_t)v.x * 64);
        const uint4* xd = (const uint4*)(xbf + (size_t)v.y * 64);
        uint4 s0 = xs[part * 2], s1 = xs[part * 2 + 1];
        uint4 d0 = xd[part * 2], d1 = xd[part * 2 + 1];
        *(uint4*)(&Af[j * APITCH + part * 16]) = s0;
        *(uint4*)(&Af[j * APITCH + part * 16 + 8]) = s1;
        *(uint4*)(&Ab[j * APITCH + part * 16]) = d0;
        *(uint4*)(&Ab[j * APITCH + part * 16 + 8]) = d1;
        if (part == 0) {
            dstF[j] = v.y;  invF[j] = 1.0f / (cntf[v.x] + 1.0f);
            dstB[j] = v.x;  invB[j] = 1.0f / (cntb[v.y] + 1.0f);
        }
    }
    __syncthreads();

    // MFMA: wave w computes edge rows [16w,16w+16) x 64 channels, both dirs
    int w = tid >> 6;
    int m = lane & 15, quad = lane >> 4;
    f32x4 zero4 = {0.f, 0.f, 0.f, 0.f};
    f32x4 accF[4] = {zero4, zero4, zero4, zero4};
    f32x4 accB[4] = {zero4, zero4, zero4, zero4};
    #pragma unroll
    for (int k0 = 0; k0 < 64; k0 += 32) {
        short8 aF = *(const short8*)(&Af[(w * 16 + m) * APITCH + k0 + quad * 8]);
        short8 aB = *(const short8*)(&Ab[(w * 16 + m) * APITCH + k0 + quad * 8]);
        #pragma unroll
        for (int n = 0; n < 4; ++n) {
            short8 bF = *(const short8*)(&Bf[(n * 16 + m) * APITCH + k0 + quad * 8]);
            short8 bB = *(const short8*)(&Bb[(n * 16 + m) * APITCH + k0 + quad * 8]);
            accF[n] = __builtin_amdgcn_mfma_f32_16x16x32_bf16(aF, bF, accF[n], 0, 0, 0);
            accB[n] = __builtin_amdgcn_mfma_f32_16x16x32_bf16(aB, bB, accB[n], 0, 0, 0);
        }
    }

    // epilogue: C/D layout col=lane&15, row=quad*4+reg; scale by 1/deg in fp32
    int row_base = w * 16 + quad * 4;
    #pragma unroll
    for (int r = 0; r < 4; ++r) {
        int row = row_base + r;
        int dF = dstF[row];
        if (dF >= 0) {
            float inv = invF[row];
            float* op = out + (size_t)dF * 64 + m;
            atomicAdd(op +  0, accF[0][r] * inv);
            atomicAdd(op + 16, accF[1][r] * inv);
            atomicAdd(op + 32, accF[2][r] * inv);
            atomicAdd(op + 48, accF[3][r] * inv);
        }
        int dB = dstB[row];
        if (dB >= 0) {
            float inv = invB[row];
            float* op = out + (size_t)dB * 64 + m;
            atomicAdd(op +  0, accB[0][r] * inv);
            atomicAdd(op + 16, accB[1][r] * inv);
            atomicAdd(op + 32, accB[2][r] * inv);
            atomicAdd(op + 48, accB[3][r] * inv);
        }
    }
}

extern "C" void kernel_launch(void* const* d_in, const int* in_sizes, int n_in,
                              void* d_out, int out_size, void* d_ws, size_t ws_size,
                              hipStream_t stream) {
    const float* x  = (const float*)d_in[0];
    const int*   ei = (const int*)  d_in[1];
    const int*   et = (const int*)  d_in[2];
    const float* wf = (const float*)d_in[3];
    const float* wb = (const float*)d_in[4];
    const float* lw = (const float*)d_in[5];
    const float* lb = (const float*)d_in[6];
    float* out = (float*)d_out;

    const int E = in_sizes[2];
    const int N = in_sizes[0] / 64;
    const int CAP = ((E + 63) >> 6) << 6;            // per-rel bucket capacity
    const int maxC = ((E + 63) >> 6) + NREL;         // 64-edge chunks upper bound

    char* p = (char*)d_ws;
    unsigned short* wtb = (unsigned short*)p;  p += (size_t)2 * NREL * 4096 * sizeof(unsigned short);
    unsigned short* xbf = (unsigned short*)p;  p += (size_t)N * 64 * sizeof(unsigned short);
    float* cntf = (float*)p;                   p += (size_t)N * sizeof(float);
    float* cntb = (float*)p;                   p += (size_t)N * sizeof(float);
    int*   fill = (int*)p;                     p += NREL * sizeof(int);
    int2*  einfo = (int2*)p;                   p += (size_t)NREL * CAP * sizeof(int2);

    const int* srcp = ei;
    const int* dstp = ei + E;

    // zero cntf, cntb, fill (contiguous)
    hipMemsetAsync(cntf, 0, ((size_t)2 * N + NREL) * sizeof(float), stream);

    const int nCountB = (E + 255) / 256;
    const int nLinB   = (N + 31) / 32;
    setup_kernel<<<nCountB + 64 + nLinB, 256, 0, stream>>>(
        x, srcp, dstp, et, wf, wb, lw, lb, cntf, cntb, fill, wtb, xbf, einfo,
        out, E, N, nCountB, CAP);
    conv_mfma<<<maxC, 256, 0, stream>>>(xbf, cntf, cntb, fill, wtb, einfo, out, CAP);
}